// Round 1
// baseline (128.706 us; speedup 1.0000x reference)
//
#include <hip/hip_runtime.h>

#define BITS 108
#define ROWF4 27  // 108 floats = 27 float4 per row (432 B, 16B-aligned)

__device__ __forceinline__ float bit_as_float(unsigned long long lo,
                                              unsigned long long hi, int k) {
    unsigned long long b = (k < 64) ? ((lo >> k) & 1ull) : ((hi >> (k - 64)) & 1ull);
    return (float)b;
}

__global__ __launch_bounds__(256) void rca108_kernel(
    const float* __restrict__ A, const float* __restrict__ B,
    float* __restrict__ S, float* __restrict__ C, int nrows)
{
    int row = blockIdx.x * blockDim.x + threadIdx.x;
    if (row >= nrows) return;

    const float4* a4 = reinterpret_cast<const float4*>(A) + (size_t)row * ROWF4;
    const float4* b4 = reinterpret_cast<const float4*>(B) + (size_t)row * ROWF4;

    unsigned long long a0 = 0, a1 = 0, b0 = 0, b1 = 0;

    #pragma unroll
    for (int j = 0; j < ROWF4; ++j) {
        float4 av = a4[j];
        float4 bv = b4[j];
        const int k = j * 4;
        unsigned long long am = (unsigned long long)(av.x > 0.5f)
                              | ((unsigned long long)(av.y > 0.5f) << 1)
                              | ((unsigned long long)(av.z > 0.5f) << 2)
                              | ((unsigned long long)(av.w > 0.5f) << 3);
        unsigned long long bm = (unsigned long long)(bv.x > 0.5f)
                              | ((unsigned long long)(bv.y > 0.5f) << 1)
                              | ((unsigned long long)(bv.z > 0.5f) << 2)
                              | ((unsigned long long)(bv.w > 0.5f) << 3);
        if (k < 64) {          // j <= 15: bits 0..63 (j=15 covers 60..63)
            a0 |= am << k;
            b0 |= bm << k;
        } else {               // j >= 16: bits 64..107
            a1 |= am << (k - 64);
            b1 |= bm << (k - 64);
        }
    }

    // 108-bit add: low 64 + high 44 with carry chain.
    unsigned long long s0 = a0 + b0;
    unsigned long long carry = (s0 < a0) ? 1ull : 0ull;
    unsigned long long s1 = a1 + b1 + carry;
    float cout = (float)((s1 >> 44) & 1ull);

    float4* s4 = reinterpret_cast<float4*>(S) + (size_t)row * ROWF4;
    #pragma unroll
    for (int j = 0; j < ROWF4; ++j) {
        const int k = j * 4;
        float4 v;
        v.x = bit_as_float(s0, s1, k + 0);
        v.y = bit_as_float(s0, s1, k + 1);
        v.z = bit_as_float(s0, s1, k + 2);
        v.w = bit_as_float(s0, s1, k + 3);
        s4[j] = v;
    }
    C[row] = cout;
}

extern "C" void kernel_launch(void* const* d_in, const int* in_sizes, int n_in,
                              void* d_out, int out_size, void* d_ws, size_t ws_size,
                              hipStream_t stream) {
    const float* A = (const float*)d_in[0];
    const float* B = (const float*)d_in[1];
    float* S = (float*)d_out;                     // [nrows, 108] flat
    int nrows = in_sizes[0] / BITS;               // 262144
    float* C = S + (size_t)nrows * BITS;          // [nrows, 1] flat, after S

    int block = 256;
    int grid = (nrows + block - 1) / block;       // 1024
    rca108_kernel<<<grid, block, 0, stream>>>(A, B, S, C, nrows);
}

// Round 2
// 76.597 us; speedup vs baseline: 1.6803x; 1.6803x over previous
//
#include <hip/hip_runtime.h>

#define BITS 108
#define RPB 256                       // rows per block (= threads per block)
#define WPR 27                        // 108 bytes = 27 u32 words per row
#define TILE_WORDS (RPB * WPR)        // 6912 u32 per operand (27,648 B)

__global__ __launch_bounds__(256) void rca108_kernel(
    const float* __restrict__ A, const float* __restrict__ B,
    float* __restrict__ S, float* __restrict__ C, int nrows)
{
    __shared__ unsigned int ldsA[TILE_WORDS];   // A bits as bytes; reused for S
    __shared__ unsigned int ldsB[TILE_WORDS];

    const int t = threadIdx.x;
    const size_t tile_base = (size_t)blockIdx.x * RPB * BITS;   // in floats

    const float4* a4 = reinterpret_cast<const float4*>(A + tile_base);
    const float4* b4 = reinterpret_cast<const float4*>(B + tile_base);

    // ---- Phase 1: coalesced load, float -> byte {0,1}, stage to LDS ----
    #pragma unroll
    for (int i = 0; i < WPR; ++i) {
        const int idx = i * RPB + t;            // float4 index == LDS word index
        const float4 av = a4[idx];
        const float4 bv = b4[idx];
        unsigned int aw = (unsigned)(av.x > 0.5f)
                        | ((unsigned)(av.y > 0.5f) << 8)
                        | ((unsigned)(av.z > 0.5f) << 16)
                        | ((unsigned)(av.w > 0.5f) << 24);
        unsigned int bw = (unsigned)(bv.x > 0.5f)
                        | ((unsigned)(bv.y > 0.5f) << 8)
                        | ((unsigned)(bv.z > 0.5f) << 16)
                        | ((unsigned)(bv.w > 0.5f) << 24);
        ldsA[idx] = aw;
        ldsB[idx] = bw;
    }
    __syncthreads();

    // ---- Phase 2: thread t owns row t; pack 27 words -> 108 bits ----
    unsigned long long a0 = 0, a1 = 0, b0 = 0, b1 = 0;
    #pragma unroll
    for (int j = 0; j < WPR; ++j) {
        unsigned int w = ldsA[t * WPR + j];
        unsigned long long nib = (unsigned long long)(
            (w & 1u) | ((w >> 7) & 2u) | ((w >> 14) & 4u) | ((w >> 21) & 8u));
        unsigned int v = ldsB[t * WPR + j];
        unsigned long long njb = (unsigned long long)(
            (v & 1u) | ((v >> 7) & 2u) | ((v >> 14) & 4u) | ((v >> 21) & 8u));
        if (j < 16) { a0 |= nib << (4 * j);        b0 |= njb << (4 * j); }
        else        { a1 |= nib << (4 * (j - 16)); b1 |= njb << (4 * (j - 16)); }
    }

    // 108-bit integer add (exact on {0,1} soft-logic inputs)
    const unsigned long long s0 = a0 + b0;
    const unsigned long long carry = (s0 < a0) ? 1ull : 0ull;
    const unsigned long long s1 = a1 + b1 + carry;
    const float cout = (float)((s1 >> 44) & 1ull);

    // ---- Phase 3: write S bytes in place over ldsA (own row only) ----
    #pragma unroll
    for (int j = 0; j < WPR; ++j) {
        const unsigned int nib = (j < 16)
            ? (unsigned int)((s0 >> (4 * j)) & 0xFull)
            : (unsigned int)((s1 >> (4 * (j - 16))) & 0xFull);
        const unsigned int w = (nib & 1u)
                             | ((nib & 2u) << 7)
                             | ((nib & 4u) << 14)
                             | ((nib & 8u) << 21);
        ldsA[t * WPR + j] = w;
    }
    __syncthreads();

    // ---- Phase 4: coalesced byte -> float4 expansion and store ----
    float4* s4 = reinterpret_cast<float4*>(S + tile_base);
    #pragma unroll
    for (int i = 0; i < WPR; ++i) {
        const int idx = i * RPB + t;
        const unsigned int w = ldsA[idx];
        float4 v;
        v.x = (float)(w & 1u);
        v.y = (float)((w >> 8) & 1u);
        v.z = (float)((w >> 16) & 1u);
        v.w = (float)((w >> 24) & 1u);
        s4[idx] = v;
    }
    C[blockIdx.x * RPB + t] = cout;
}

extern "C" void kernel_launch(void* const* d_in, const int* in_sizes, int n_in,
                              void* d_out, int out_size, void* d_ws, size_t ws_size,
                              hipStream_t stream) {
    const float* A = (const float*)d_in[0];
    const float* B = (const float*)d_in[1];
    float* S = (float*)d_out;                    // [nrows, 108] flat
    const int nrows = in_sizes[0] / BITS;        // 262144
    float* C = S + (size_t)nrows * BITS;         // [nrows, 1] after S

    const int grid = nrows / RPB;                // 1024 (exact)
    rca108_kernel<<<grid, RPB, 0, stream>>>(A, B, S, C, nrows);
}